// Round 6
// baseline (316.293 us; speedup 1.0000x reference)
//
#include <hip/hip_runtime.h>

// NeuS-style renderer sampling (all fp32):
//  inputs: ray_dirs (1,262144,3), cam_loc (1,3), t_rand (262144,64)
//  outputs (concat): new_samples (P,32,3), z_samples (P,32), weights (P,63)
//
// Round 9: kill the serial cross-lane chains. Round-8 (-6 us) showed the
// constant-offset scans were already DPP; render (~115-125 us vs ~55 us
// pipe/BW floor) is latency-bound on (a) the strictly serial 6-probe
// bpermute binary search + 6 bpermute gathers (~12 x ~35cyc dependent),
// and (b) the tr load used immediately at each ray-loop head (~900 cyc
// exposed). This round:
//  - interval-ownership inversion: lane j owns cdf interval [D_{j-1},D_j);
//    u_i=(2i+1)/64 is a fixed grid, so lane j directly computes its owned
//    sample range via h_j = ceil((64*D_j-1)/2), i in [h_{j-1}, h_j).
//    Neighbors via constant-offset DPP (no DS). ZERO bpermutes remain.
//    z redistributed through a 128 B/wave LDS scratch (same-wave, no bar).
//  - software prefetch of next ray's tr + rd (hidden under current compute).

static constexpr int NSTEPS = 64;
static constexpr int NIMP   = 32;

// DPP update: dest = (src permuted by CTRL) where valid+row-selected, else OLD.
// CTRL: 0x111/0x112/0x114/0x118 = row_shr:1/2/4/8; 0x142 row_bcast:15;
//       0x143 row_bcast:31; 0x130 wf_shl:1 (lane i <- i+1); 0x138 wf_shr:1
//       (lane i <- i-1). Verified on HW by rounds 8/9 passes.
template<int CTRL, int RM>
__device__ __forceinline__ float upd_dpp_f(float old, float src){
  return __int_as_float(__builtin_amdgcn_update_dpp(
      __float_as_int(old), __float_as_int(src), CTRL, RM, 0xF, false));
}
template<int CTRL, int RM>
__device__ __forceinline__ int upd_dpp_i(int old, int src){
  return __builtin_amdgcn_update_dpp(old, src, CTRL, RM, 0xF, false);
}

// inclusive 64-lane scans, all on the VALU pipe (identity fills via OLD)
__device__ __forceinline__ float mul_scan64(float x){
  x *= upd_dpp_f<0x111,0xF>(1.0f, x);
  x *= upd_dpp_f<0x112,0xF>(1.0f, x);
  x *= upd_dpp_f<0x114,0xF>(1.0f, x);
  x *= upd_dpp_f<0x118,0xF>(1.0f, x);
  x *= upd_dpp_f<0x142,0xa>(1.0f, x);   // row1,3 *= total(row0 / row2)
  x *= upd_dpp_f<0x143,0xc>(1.0f, x);   // rows2,3 *= total(lanes 0..31)
  return x;
}
__device__ __forceinline__ float add_scan64(float x){
  x += upd_dpp_f<0x111,0xF>(0.0f, x);
  x += upd_dpp_f<0x112,0xF>(0.0f, x);
  x += upd_dpp_f<0x114,0xF>(0.0f, x);
  x += upd_dpp_f<0x118,0xF>(0.0f, x);
  x += upd_dpp_f<0x142,0xa>(0.0f, x);
  x += upd_dpp_f<0x143,0xc>(0.0f, x);
  return x;
}

// ---------- pass 1a: per-block partial sums over hit rays ----------
__global__ __launch_bounds__(256) void si_partial_kernel(
    const float* __restrict__ rd, const float* __restrict__ cam,
    float* __restrict__ partial, int P)
{
  float cx = cam[0], cy = cam[1], cz = cam[2];
  float c2m = cx*cx + cy*cy + cz*cz - 1.0f;   // |cam|^2 - R^2, R=1
  float s0 = 0.f, s1 = 0.f, cnt = 0.f;
  int stride = gridDim.x * blockDim.x;
  for (int p = blockIdx.x * blockDim.x + threadIdx.x; p < P; p += stride){
    float dx = rd[3*p+0], dy = rd[3*p+1], dz = rd[3*p+2];
    float rcd = dx*cx + dy*cy + dz*cz;
    float under = rcd*rcd - c2m;
    if (under > 0.f){
      float sq = sqrtf(under);
      s0 += -sq - rcd; s1 += sq - rcd; cnt += 1.f;
    }
  }
  #pragma unroll
  for (int off = 32; off > 0; off >>= 1){
    s0  += __shfl_down(s0,  off, 64);
    s1  += __shfl_down(s1,  off, 64);
    cnt += __shfl_down(cnt, off, 64);
  }
  __shared__ float sh[3][4];
  int w = threadIdx.x >> 6;
  if ((threadIdx.x & 63) == 0){ sh[0][w] = s0; sh[1][w] = s1; sh[2][w] = cnt; }
  __syncthreads();
  if (threadIdx.x == 0){
    partial[blockIdx.x*3+0] = sh[0][0]+sh[0][1]+sh[0][2]+sh[0][3];
    partial[blockIdx.x*3+1] = sh[1][0]+sh[1][1]+sh[1][2]+sh[1][3];
    partial[blockIdx.x*3+2] = sh[2][0]+sh[2][1]+sh[2][2]+sh[2][3];
  }
}

// ---------- pass 1b: reduce partials -> ws[0..2] ----------
__global__ __launch_bounds__(256) void si_final_kernel(
    const float* __restrict__ partial, float* __restrict__ ws, int nblk)
{
  float s0 = 0.f, s1 = 0.f, cnt = 0.f;
  for (int b = threadIdx.x; b < nblk; b += 256){
    s0 += partial[3*b+0]; s1 += partial[3*b+1]; cnt += partial[3*b+2];
  }
  #pragma unroll
  for (int off = 32; off > 0; off >>= 1){
    s0  += __shfl_down(s0,  off, 64);
    s1  += __shfl_down(s1,  off, 64);
    cnt += __shfl_down(cnt, off, 64);
  }
  __shared__ float sh[3][4];
  int w = threadIdx.x >> 6;
  if ((threadIdx.x & 63) == 0){ sh[0][w] = s0; sh[1][w] = s1; sh[2][w] = cnt; }
  __syncthreads();
  if (threadIdx.x == 0){
    ws[0] = sh[0][0]+sh[0][1]+sh[0][2]+sh[0][3];
    ws[1] = sh[1][0]+sh[1][1]+sh[1][2]+sh[1][3];
    ws[2] = sh[2][0]+sh[2][1]+sh[2][2]+sh[2][3];
  }
}

// ---------- pass 2: WAVE per ray; lane = step index ----------
__global__ __launch_bounds__(256) void render_wave_kernel(
    const float* __restrict__ rd, const float* __restrict__ cam,
    const float* __restrict__ tr, const float* __restrict__ ws,
    float* __restrict__ out, int P)
{
  __shared__ float zb[4][32];                 // per-wave z scratch (128 B/wave)
  const int lane = threadIdx.x & 63;
  const int wv   = threadIdx.x >> 6;
  const int wid  = (int)((blockIdx.x * blockDim.x + threadIdx.x) >> 6);
  const int nw   = (int)((gridDim.x * blockDim.x) >> 6);

  const float cx = cam[0], cy = cam[1], cz = cam[2];
  const float c2m = cx*cx + cy*cy + cz*cz - 1.0f;   // |cam|^2 - R^2
  const float nh = fmaxf(ws[2], 1.0f);
  const float m0 = ws[0] / nh, m1 = ws[1] / nh;     // mean si fallback

  const float inv_s = 20.085536923187668f;          // exp(0.3*10)
  const float jf = (float)lane * (1.0f/63.0f);      // linspace(0,1,64)[lane]

  // new_samples emission constants: element e -> z[e/3]*d[e%3]+c[e%3]
  const int e2 = 64 + lane;
  const int q1 = lane / 3, r1 = lane - 3*q1;        // e1 = lane (0..63)
  const int q2 = e2  / 3, r2 = e2  - 3*q2;          // e2 = 64+lane (lanes 0..31)

  float* __restrict__ wbase = out + (size_t)P*128;  // weights region
  float* __restrict__ zbase = out + (size_t)P*96;   // z_samples region

  if (wid >= P) return;

  // ---- prefetch ray 0's inputs ----
  float dx = rd[3*wid+0], dy = rd[3*wid+1], dz = rd[3*wid+2];
  float t  = tr[(size_t)wid*64 + lane];             // coalesced 256B/wave

  for (int p = wid; p < P; p += nw){
    // ---- issue NEXT ray's loads early (latency hidden under compute) ----
    const int pn = p + nw;
    const bool hasn = pn < P;                       // wave-uniform
    float dxn = 0.f, dyn = 0.f, dzn = 0.f, tn = 0.f;
    if (hasn){
      dxn = rd[3*pn+0]; dyn = rd[3*pn+1]; dzn = rd[3*pn+2];
      tn  = tr[(size_t)pn*64 + lane];
    }

    // ---- ray setup (wave-uniform branch) ----
    float rcd = dx*cx + dy*cy + dz*cz;
    float under = rcd*rcd - c2m;
    float si0, si1;
    if (under > 0.f){
      float sq = sqrtf(under);
      si0 = -sq - rcd; si1 = sq - rcd;
    } else {
      si0 = m0; si1 = m1;
    }
    float min_d = fmaxf(si0, 0.f), max_d = fmaxf(si1, 0.f);
    float range = max_d - min_d;
    float sdist = range * (1.0f/64.0f);      // (max-min)/N_STEPS

    // ---- per-lane step, sdf, sigmoid ----
    float s = fmaf(range, jf, min_d) + (t - 0.5f) * sdist;
    float px = fmaf(s,dx,cx), py = fmaf(s,dy,cy), pz = fmaf(s,dz,cz);
    float c  = 1.0f / (1.0f + __expf(-(sqrtf(px*px+py*py+pz*pz) - 0.5f) * inv_s));

    // ---- alpha_j from (c_j, c_{j+1}); valid lanes 0..62 (DPP wf_shl:1) ----
    float cnx = upd_dpp_f<0x130,0xF>(c, c);  // lane i <- c[i+1]; lane63 = c
    float a = (c - cnx + 1e-8f) / (c + 1e-8f);
    a = fminf(fmaxf(a, 0.f), 1.0f);

    // ---- trans = exclusive cumprod of (1-a+1e-7), DPP mul-scan ----
    float f = (lane < 63) ? (1.0f - a + 1e-7f) : 1.0f;
    float incl = mul_scan64(f);
    float trans = upd_dpp_f<0x138,0xF>(1.0f, incl);  // lane i <- i-1; lane0=1

    // ---- weights (lanes 0..62): direct coalesced store ----
    float w = a * trans;
    if (lane < 63) wbase[(size_t)p*63 + lane] = w;

    // ---- normalized CDF via DPP add-scan; D_j = cdf_full[j+1] ----
    float wp = (lane < 63) ? (w + 1e-8f) : 0.0f;
    float D = add_scan64(wp);
    float Tp = __int_as_float(
        __builtin_amdgcn_readlane(__float_as_int(D), 62)); // sum of 63 entries
    D *= (1.0f / Tp);                         // D_62 = 1 (+-1ulp); D_63 = D_62

    // ---- interval ownership: lane j owns u_i in [D_{j-1}, D_j) ----
    // h_j = #{i : u_i < D_j} = ceil((64*D_j - 1)/2); owned i in [h_{j-1},h_j).
    // Exactly matches searchsorted 'right' (ties: u==D_{j-1} -> owner j).
    float Dm1 = upd_dpp_f<0x138,0xF>(0.0f, D);        // lane j <- D[j-1]; 0@0
    float s1l = upd_dpp_f<0x130,0xF>(s, s);           // lane j <- s[j+1]
    int h = (int)ceilf(fmaf(64.0f, D, -1.0f) * 0.5f);
    h = max(0, min(32, h));
    int hm1 = upd_dpp_i<0x138,0xF>(0, h);             // h_{j-1}; 0 @ lane0
    float den = D - Dm1;
    if (den < 1e-8f) den = 1.0f;
    float rden = 1.0f / den;
    // divergent emit loop: avg c_j ~ 0.5, wave cost = max_j c_j (small for
    // smooth weights; bounded by 32). Disjoint-bank ds_writes.
    for (int i = hm1; i < h; ++i){
      float u_i = (float)(2*i + 1) * (1.0f/64.0f);
      float tq = (u_i - Dm1) * rden;
      zb[wv][i] = fmaf(tq, s1l - s, s);
    }
    // same-wave LDS readback (program order + lgkmcnt; no barrier needed)
    float z  = zb[wv][lane & 31];
    float z1 = zb[wv][q1];                            // broadcast-friendly
    float z2 = zb[wv][q2];
    if (lane < 32) zbase[(size_t)p*32 + lane] = z;

    // ---- new_samples: 96 floats = cam + z[e/3]*dir[e%3]; two stores ----
    float dd1 = (r1 == 0) ? dx : ((r1 == 1) ? dy : dz);
    float cc1 = (r1 == 0) ? cx : ((r1 == 1) ? cy : cz);
    out[(size_t)p*96 + lane] = fmaf(z1, dd1, cc1);
    if (lane < 32){
      float dd2 = (r2 == 0) ? dx : ((r2 == 1) ? dy : dz);
      float cc2 = (r2 == 0) ? cx : ((r2 == 1) ? cy : cz);
      out[(size_t)p*96 + e2] = fmaf(z2, dd2, cc2);
    }

    // ---- rotate prefetched inputs ----
    dx = dxn; dy = dyn; dz = dzn; t = tn;
  }
}

extern "C" void kernel_launch(void* const* d_in, const int* in_sizes, int n_in,
                              void* d_out, int out_size, void* d_ws, size_t ws_size,
                              hipStream_t stream) {
  const float* rd  = (const float*)d_in[0];
  const float* cam = (const float*)d_in[1];
  const float* tr  = (const float*)d_in[2];
  float* out = (float*)d_out;
  float* ws  = (float*)d_ws;       // ws[0..2] = mean_si sums; ws+8.. = partials
  const int P = in_sizes[0] / 3;   // 262144 rays

  const int RBLK = 256;
  si_partial_kernel<<<RBLK, 256, 0, stream>>>(rd, cam, ws + 8, P);
  si_final_kernel<<<1, 256, 0, stream>>>(ws + 8, ws, RBLK);
  // 2048 blocks = 8 blocks/CU, 32 waves/CU (512 B LDS): full occupancy.
  render_wave_kernel<<<2048, 256, 0, stream>>>(rd, cam, tr, ws, out, P);
}